// Round 9
// baseline (359.047 us; speedup 1.0000x reference)
//
#include <hip/hip_runtime.h>
#include <hip/hip_bf16.h>
#include <math.h>

#define N_NODES 80000
#define N_EDGES 640000
#define B_GR 800
#define NPG 100
#define HID 128
#define NC 10
#define IND 20
#define BN_EPS 1e-5f
#define NBLK_SCAN 313   // ceil(80000/256)

// ---------- degree counting ----------
__global__ void k_deg(const int* __restrict__ src, const int* __restrict__ dst,
                      int* in_deg, int* out_deg) {
    int e = blockIdx.x * blockDim.x + threadIdx.x;
    if (e < N_EDGES) {
        atomicAdd(&in_deg[dst[e]], 1);
        atomicAdd(&out_deg[src[e]], 1);
    }
}

__global__ void k_nodeprep(const int* __restrict__ in_deg, const int* __restrict__ out_deg,
                           float* inv_in, float* inv_out, int* idx) {
    int n = blockIdx.x * blockDim.x + threadIdx.x;
    if (n < N_NODES) {
        float fi = (float)in_deg[n];
        float fo = (float)out_deg[n];
        inv_in[n]  = rsqrtf(fmaxf(fi, 1.f));
        inv_out[n] = rsqrtf(fmaxf(fo, 1.f));
        int k = in_deg[n]; if (k > IND - 1) k = IND - 1;
        idx[n] = k;
    }
}

// ---------- CSR build: exclusive scan of in_deg, then scatter ----------
__global__ __launch_bounds__(256) void k_scan1(const int* __restrict__ in, int* part, int* bsum) {
    __shared__ int s[256];
    int t = threadIdx.x, i = blockIdx.x * 256 + t;
    int v = (i < N_NODES) ? in[i] : 0;
    s[t] = v; __syncthreads();
    for (int d = 1; d < 256; d <<= 1) {
        int x = (t >= d) ? s[t - d] : 0;
        __syncthreads();
        s[t] += x;
        __syncthreads();
    }
    if (i < N_NODES) part[i] = s[t] - v;            // exclusive partial
    if (t == 255) bsum[blockIdx.x] = s[255];        // block total
}

__global__ __launch_bounds__(512) void k_scan2(const int* __restrict__ bsum, int* boff) {
    __shared__ int s[512];
    int t = threadIdx.x;
    int v = (t < NBLK_SCAN) ? bsum[t] : 0;
    s[t] = v; __syncthreads();
    for (int d = 1; d < 512; d <<= 1) {
        int x = (t >= d) ? s[t - d] : 0;
        __syncthreads();
        s[t] += x;
        __syncthreads();
    }
    if (t < NBLK_SCAN) boff[t] = s[t] - v;          // exclusive
}

__global__ __launch_bounds__(256) void k_scan3(int* csr_off, const int* __restrict__ boff,
                                               int* cursor) {
    int i = blockIdx.x * 256 + threadIdx.x;
    if (i < N_NODES) {
        int v = csr_off[i] + boff[blockIdx.x];
        csr_off[i] = v;
        cursor[i] = v;
    }
    if (i == 0) csr_off[N_NODES] = N_EDGES;
}

// fused: CSR scatter + layer-1 one-hot aggregation (single edge pass)
__global__ void k_scatter_l1(const int* __restrict__ src, const int* __restrict__ dst,
                             const int* __restrict__ idx, const float* __restrict__ inv_out,
                             int* cursor, int* csr_src, float* agg20) {
    int e = blockIdx.x * blockDim.x + threadIdx.x;
    if (e < N_EDGES) {
        int s = src[e], t = dst[e];
        int pos = atomicAdd(&cursor[t], 1);
        csr_src[pos] = s;
        atomicAdd(&agg20[t * IND + idx[s]], inv_out[s]);
    }
}

// ---------- BN1 stats via moments ----------
#define MOM_CHUNK 64
__global__ __launch_bounds__(256) void k_mom(const float* __restrict__ agg20,
                                             const float* __restrict__ inv_in,
                                             float* s20, float* Mbuf) {
    __shared__ float rows[MOM_CHUNK * IND];
    __shared__ float w1s[MOM_CHUNK], w2s[MOM_CHUNK];
    int t = threadIdx.x;
    int k = 0, l = 0;
    bool isM = (t < 210), isS = (t >= 210 && t < 230);
    if (isM) {
        int idx = t, kk = 0;
        while (idx >= IND - kk) { idx -= IND - kk; ++kk; }
        k = kk; l = kk + idx;
    } else if (isS) {
        k = t - 210;
    }
    float acc = 0.f;
    for (int c = blockIdx.x; c < N_NODES / MOM_CHUNK; c += gridDim.x) {
        __syncthreads();
        for (int i = t * 4; i < MOM_CHUNK * IND; i += 1024)
            *(float4*)&rows[i] = *(const float4*)&agg20[(size_t)c * MOM_CHUNK * IND + i];
        if (t < MOM_CHUNK) {
            float v = inv_in[c * MOM_CHUNK + t];
            w1s[t] = v; w2s[t] = v * v;
        }
        __syncthreads();
        if (isM) {
            for (int i = 0; i < MOM_CHUNK; ++i)
                acc += w2s[i] * rows[i * IND + k] * rows[i * IND + l];
        } else if (isS) {
            for (int i = 0; i < MOM_CHUNK; ++i)
                acc += w1s[i] * rows[i * IND + k];
        }
    }
    if (isM) atomicAdd(&Mbuf[t], acc);
    else if (isS) atomicAdd(&s20[t - 210], acc);
}

// a1,c1 from moments (128 threads: each stages TWO sM entries; first 20 stage ss)
__global__ void k_bn1fin(const float* __restrict__ s20, const float* __restrict__ Mbuf,
                         const float* __restrict__ W1, const float* __restrict__ b1,
                         const float* __restrict__ g1, const float* __restrict__ be1,
                         float* a1, float* c1) {
    __shared__ float sM[210], ss[IND];
    int j = threadIdx.x;
    if (j < 210) sM[j] = Mbuf[j];
    if (j + 128 < 210) sM[j + 128] = Mbuf[j + 128];
    if (j < IND) ss[j] = s20[j];
    __syncthreads();
    float w[IND];
#pragma unroll
    for (int k = 0; k < IND; ++k) w[k] = W1[k * HID + j];
    float tj = 0.f;
#pragma unroll
    for (int k = 0; k < IND; ++k) tj += ss[k] * w[k];
    float q = 0.f;
    int idx = 0;
#pragma unroll
    for (int k = 0; k < IND; ++k) {
        q += sM[idx] * w[k] * w[k]; ++idx;
#pragma unroll
        for (int l = k + 1; l < IND; ++l) { q += 2.f * sM[idx] * w[k] * w[l]; ++idx; }
    }
    float bj = b1[j];
    const float Nf = (float)N_NODES;
    float mean = (tj + Nf * bj) / Nf;
    float ey2  = (q + 2.f * bj * tj + Nf * bj * bj) / Nf;
    float var  = ey2 - mean * mean;
    float aj = g1[j] / sqrtf(var + BN_EPS);
    a1[j] = aj;
    c1[j] = be1[j] - mean * aj;
}

// ---------- fused layer 1: h1s = elu(bn(inv_in*(agg20@W1)+b1)) * inv_out ----------
__global__ __launch_bounds__(256) void k_l1f(const float* __restrict__ agg20,
                                             const float* __restrict__ inv_in,
                                             const float* __restrict__ inv_out,
                                             const float* __restrict__ W1,
                                             const float* __restrict__ b1,
                                             const float* __restrict__ a1,
                                             const float* __restrict__ c1,
                                             float* __restrict__ h1s) {
    __shared__ float ws[IND * HID];   // 10 KB
    int t = threadIdx.x;
    for (int i = t * 4; i < IND * HID; i += 1024)
        *(float4*)&ws[i] = *(const float4*)&W1[i];
    __syncthreads();
    int tx = t & 15, ty = t >> 4;
    int c0 = tx * 8;
    float4 ba = *(const float4*)(b1 + c0);
    float4 bb = *(const float4*)(b1 + c0 + 4);
    float4 aa = *(const float4*)(a1 + c0);
    float4 ab = *(const float4*)(a1 + c0 + 4);
    float4 ca = *(const float4*)(c1 + c0);
    float4 cb = *(const float4*)(c1 + c0 + 4);

    int row0 = blockIdx.x * 64 + ty * 4;
    const float* xr0 = agg20 + (size_t)row0 * IND;
    const float* xr1 = xr0 + IND;
    const float* xr2 = xr1 + IND;
    const float* xr3 = xr2 + IND;
    float acc[4][8];
#pragma unroll
    for (int r = 0; r < 4; ++r)
#pragma unroll
        for (int c = 0; c < 8; ++c) acc[r][c] = 0.f;

#pragma unroll
    for (int k = 0; k < IND; k += 4) {
        float4 x0 = *(const float4*)(xr0 + k);
        float4 x1 = *(const float4*)(xr1 + k);
        float4 x2 = *(const float4*)(xr2 + k);
        float4 x3 = *(const float4*)(xr3 + k);
#pragma unroll
        for (int kk = 0; kk < 4; ++kk) {
            float4 wa = *(const float4*)&ws[(k + kk) * HID + c0];
            float4 wb = *(const float4*)&ws[(k + kk) * HID + c0 + 4];
            float xk0 = (kk == 0) ? x0.x : (kk == 1) ? x0.y : (kk == 2) ? x0.z : x0.w;
            float xk1 = (kk == 0) ? x1.x : (kk == 1) ? x1.y : (kk == 2) ? x1.z : x1.w;
            float xk2 = (kk == 0) ? x2.x : (kk == 1) ? x2.y : (kk == 2) ? x2.z : x2.w;
            float xk3 = (kk == 0) ? x3.x : (kk == 1) ? x3.y : (kk == 2) ? x3.z : x3.w;
            acc[0][0] += xk0 * wa.x; acc[0][1] += xk0 * wa.y;
            acc[0][2] += xk0 * wa.z; acc[0][3] += xk0 * wa.w;
            acc[0][4] += xk0 * wb.x; acc[0][5] += xk0 * wb.y;
            acc[0][6] += xk0 * wb.z; acc[0][7] += xk0 * wb.w;
            acc[1][0] += xk1 * wa.x; acc[1][1] += xk1 * wa.y;
            acc[1][2] += xk1 * wa.z; acc[1][3] += xk1 * wa.w;
            acc[1][4] += xk1 * wb.x; acc[1][5] += xk1 * wb.y;
            acc[1][6] += xk1 * wb.z; acc[1][7] += xk1 * wb.w;
            acc[2][0] += xk2 * wa.x; acc[2][1] += xk2 * wa.y;
            acc[2][2] += xk2 * wa.z; acc[2][3] += xk2 * wa.w;
            acc[2][4] += xk2 * wb.x; acc[2][5] += xk2 * wb.y;
            acc[2][6] += xk2 * wb.z; acc[2][7] += xk2 * wb.w;
            acc[3][0] += xk3 * wa.x; acc[3][1] += xk3 * wa.y;
            acc[3][2] += xk3 * wa.z; acc[3][3] += xk3 * wa.w;
            acc[3][4] += xk3 * wb.x; acc[3][5] += xk3 * wb.y;
            acc[3][6] += xk3 * wb.z; acc[3][7] += xk3 * wb.w;
        }
    }
    float4 iv = *(const float4*)(inv_in + row0);
    float4 ov = *(const float4*)(inv_out + row0);
#pragma unroll
    for (int r = 0; r < 4; ++r) {
        float ivr = (r == 0) ? iv.x : (r == 1) ? iv.y : (r == 2) ? iv.z : iv.w;
        float ovr = (r == 0) ? ov.x : (r == 1) ? ov.y : (r == 2) ? ov.z : ov.w;
        float y[8];
        y[0] = acc[r][0] * ivr + ba.x; y[1] = acc[r][1] * ivr + ba.y;
        y[2] = acc[r][2] * ivr + ba.z; y[3] = acc[r][3] * ivr + ba.w;
        y[4] = acc[r][4] * ivr + bb.x; y[5] = acc[r][5] * ivr + bb.y;
        y[6] = acc[r][6] * ivr + bb.z; y[7] = acc[r][7] * ivr + bb.w;
        float z[8];
        z[0] = y[0] * aa.x + ca.x; z[1] = y[1] * aa.y + ca.y;
        z[2] = y[2] * aa.z + ca.z; z[3] = y[3] * aa.w + ca.w;
        z[4] = y[4] * ab.x + cb.x; z[5] = y[5] * ab.y + cb.y;
        z[6] = y[6] * ab.z + cb.z; z[7] = y[7] * ab.w + cb.w;
#pragma unroll
        for (int c = 0; c < 8; ++c) {
            float h = z[c] > 0.f ? z[c] : expm1f(z[c]);
            z[c] = h * ovr;
        }
        float* yr = h1s + (size_t)(row0 + r) * HID + c0;
        *(float4*)yr = make_float4(z[0], z[1], z[2], z[3]);
        *(float4*)(yr + 4) = make_float4(z[4], z[5], z[6], z[7]);
    }
}

// ---------- layer-2 aggregation v3: block per graph, h1 slice staged in LDS ----------
__global__ __launch_bounds__(512) void k_agg2(const int* __restrict__ csr_off,
                                              const int* __restrict__ csr_src,
                                              const float* __restrict__ h1s,
                                              float* __restrict__ agg2) {
    __shared__ float sh[NPG * HID];   // 51200 B
    int t = threadIdx.x;
    int g = blockIdx.x;
    int gbase = g * NPG;

    const float4* srcp = (const float4*)(h1s + (size_t)gbase * HID);
    float4* shp = (float4*)sh;
    for (int i = t; i < (NPG * HID) / 4; i += 512)
        shp[i] = srcp[i];
    __syncthreads();

    int wv = t >> 6, lane = t & 63;
    for (int r = wv; r < NPG; r += 8) {
        int n = gbase + r;
        int e0 = csr_off[n], e1 = csr_off[n + 1];
        float ax = 0.f, ay = 0.f;
        int e = e0;
        for (; e + 4 <= e1; e += 4) {
            int s0 = csr_src[e]     - gbase;
            int s1 = csr_src[e + 1] - gbase;
            int s2 = csr_src[e + 2] - gbase;
            int s3 = csr_src[e + 3] - gbase;
            float2 v0 = *(const float2*)&sh[s0 * HID + lane * 2];
            float2 v1 = *(const float2*)&sh[s1 * HID + lane * 2];
            float2 v2 = *(const float2*)&sh[s2 * HID + lane * 2];
            float2 v3 = *(const float2*)&sh[s3 * HID + lane * 2];
            ax += (v0.x + v1.x) + (v2.x + v3.x);
            ay += (v0.y + v1.y) + (v2.y + v3.y);
        }
        for (; e < e1; ++e) {
            int s = csr_src[e] - gbase;
            float2 v = *(const float2*)&sh[s * HID + lane * 2];
            ax += v.x; ay += v.y;
        }
        *(float2*)(agg2 + (size_t)n * HID + lane * 2) = make_float2(ax, ay);
    }
}

// ---------- BN finalize (layers 2,3) ----------
__global__ void k_bnfin(const float* sums, const float* sqs,
                        const float* gamma, const float* beta,
                        float cnt, float* a, float* c) {
    int j = threadIdx.x;
    float mu  = sums[j] / cnt;
    float var = sqs[j] / cnt - mu * mu;
    float aj  = gamma[j] / sqrtf(var + BN_EPS);
    a[j] = aj;
    c[j] = beta[j] - mu * aj;
}

// ---------- layer 2 GEMM v4: 512 thr, 128-row tile, conflict-free W reads ----------
// Thread (tx,ty): cols [tx*4,tx*4+4) and [64+tx*4, 64+tx*4+4); rows ty*4..ty*4+3.
// LDS W reads: 16 lanes x float4 at stride 4 dwords = 64 contiguous dwords -> 2 lanes/bank (free).
__global__ __launch_bounds__(512) void k_l2v4(const float* __restrict__ xin,
                                              const float* __restrict__ inv_in,
                                              const float* __restrict__ W,
                                              const float* __restrict__ bvec,
                                              float* __restrict__ yout,
                                              float* sums, float* sqs) {
    __shared__ float ws[HID * HID];   // 64 KB; 2 blocks/CU = 128KB <= 160KB
    int t = threadIdx.x;
    for (int i = t * 4; i < HID * HID; i += 2048)
        *(float4*)&ws[i] = *(const float4*)&W[i];
    __syncthreads();

    int tx = t & 15;           // 16 col groups
    int ty = t >> 4;           // 32 row groups x 4 rows = 128-row tile
    int c0a = tx * 4;
    int c0b = 64 + tx * 4;
    float4 ba = *(const float4*)(bvec + c0a);
    float4 bb = *(const float4*)(bvec + c0b);
    float csum[8], csq[8];
#pragma unroll
    for (int c = 0; c < 8; ++c) { csum[c] = 0.f; csq[c] = 0.f; }

    for (int tile = blockIdx.x; tile < N_NODES / 128; tile += gridDim.x) {
        int row0 = tile * 128 + ty * 4;
        const float* xr0 = xin + (size_t)row0 * HID;
        const float* xr1 = xr0 + HID;
        const float* xr2 = xr1 + HID;
        const float* xr3 = xr2 + HID;
        float acc[4][8];
#pragma unroll
        for (int r = 0; r < 4; ++r)
#pragma unroll
            for (int c = 0; c < 8; ++c) acc[r][c] = 0.f;

#pragma unroll 4
        for (int k = 0; k < HID; k += 4) {
            float4 x0 = *(const float4*)(xr0 + k);
            float4 x1 = *(const float4*)(xr1 + k);
            float4 x2 = *(const float4*)(xr2 + k);
            float4 x3 = *(const float4*)(xr3 + k);
#pragma unroll
            for (int kk = 0; kk < 4; ++kk) {
                float4 wa = *(const float4*)&ws[(k + kk) * HID + c0a];
                float4 wb = *(const float4*)&ws[(k + kk) * HID + c0b];
                float xk0 = (kk == 0) ? x0.x : (kk == 1) ? x0.y : (kk == 2) ? x0.z : x0.w;
                float xk1 = (kk == 0) ? x1.x : (kk == 1) ? x1.y : (kk == 2) ? x1.z : x1.w;
                float xk2 = (kk == 0) ? x2.x : (kk == 1) ? x2.y : (kk == 2) ? x2.z : x2.w;
                float xk3 = (kk == 0) ? x3.x : (kk == 1) ? x3.y : (kk == 2) ? x3.z : x3.w;
                acc[0][0] += xk0 * wa.x; acc[0][1] += xk0 * wa.y;
                acc[0][2] += xk0 * wa.z; acc[0][3] += xk0 * wa.w;
                acc[0][4] += xk0 * wb.x; acc[0][5] += xk0 * wb.y;
                acc[0][6] += xk0 * wb.z; acc[0][7] += xk0 * wb.w;
                acc[1][0] += xk1 * wa.x; acc[1][1] += xk1 * wa.y;
                acc[1][2] += xk1 * wa.z; acc[1][3] += xk1 * wa.w;
                acc[1][4] += xk1 * wb.x; acc[1][5] += xk1 * wb.y;
                acc[1][6] += xk1 * wb.z; acc[1][7] += xk1 * wb.w;
                acc[2][0] += xk2 * wa.x; acc[2][1] += xk2 * wa.y;
                acc[2][2] += xk2 * wa.z; acc[2][3] += xk2 * wa.w;
                acc[2][4] += xk2 * wb.x; acc[2][5] += xk2 * wb.y;
                acc[2][6] += xk2 * wb.z; acc[2][7] += xk2 * wb.w;
                acc[3][0] += xk3 * wa.x; acc[3][1] += xk3 * wa.y;
                acc[3][2] += xk3 * wa.z; acc[3][3] += xk3 * wa.w;
                acc[3][4] += xk3 * wb.x; acc[3][5] += xk3 * wb.y;
                acc[3][6] += xk3 * wb.z; acc[3][7] += xk3 * wb.w;
            }
        }
        float4 iv = *(const float4*)(inv_in + tile * 128 + ty * 4);
#pragma unroll
        for (int r = 0; r < 4; ++r) {
            float ivr = (r == 0) ? iv.x : (r == 1) ? iv.y : (r == 2) ? iv.z : iv.w;
            float y[8];
            y[0] = acc[r][0] * ivr + ba.x; y[1] = acc[r][1] * ivr + ba.y;
            y[2] = acc[r][2] * ivr + ba.z; y[3] = acc[r][3] * ivr + ba.w;
            y[4] = acc[r][4] * ivr + bb.x; y[5] = acc[r][5] * ivr + bb.y;
            y[6] = acc[r][6] * ivr + bb.z; y[7] = acc[r][7] * ivr + bb.w;
#pragma unroll
            for (int c = 0; c < 8; ++c) { csum[c] += y[c]; csq[c] += y[c] * y[c]; }
            float* yr = yout + (size_t)(row0 + r) * HID;
            *(float4*)(yr + c0a) = make_float4(y[0], y[1], y[2], y[3]);
            *(float4*)(yr + c0b) = make_float4(y[4], y[5], y[6], y[7]);
        }
    }

    // column stats: ws reused (W done). sums at ws[0..4095], sqs at ws[4096..8191]
    __syncthreads();
#pragma unroll
    for (int c = 0; c < 4; ++c) {
        ws[ty * HID + c0a + c] = csum[c];
        ws[ty * HID + c0b + c] = csum[4 + c];
        ws[4096 + ty * HID + c0a + c] = csq[c];
        ws[4096 + ty * HID + c0b + c] = csq[4 + c];
    }
    __syncthreads();
    if (t < HID) {
        float s1 = 0.f, s2 = 0.f;
#pragma unroll
        for (int r = 0; r < 32; ++r) {
            s1 += ws[r * HID + t];
            s2 += ws[4096 + r * HID + t];
        }
        atomicAdd(&sums[t], s1);
        atomicAdd(&sqs[t], s2);
    }
}

// in-place y2 -> h2 (elu), p[n] = inv_out[n]*dot(h2[n],Wv); wave per row
__global__ __launch_bounds__(256) void k_elu2_p(float* buf,
                                                const float* __restrict__ a,
                                                const float* __restrict__ c,
                                                const float* __restrict__ inv_out,
                                                const float* __restrict__ Wv,
                                                float* __restrict__ p) {
    int lane = threadIdx.x & 63;
    int wid = (blockIdx.x * blockDim.x + threadIdx.x) >> 6;
    int nw = (gridDim.x * blockDim.x) >> 6;
    float2 av = *(const float2*)(a + lane * 2);
    float2 cv = *(const float2*)(c + lane * 2);
    float2 wv = *(const float2*)(Wv + lane * 2);
    for (int n = wid; n < N_NODES; n += nw) {
        float2* row = (float2*)(buf + (size_t)n * HID);
        float2 x = row[lane];
        float h0 = x.x * av.x + cv.x; h0 = h0 > 0.f ? h0 : expm1f(h0);
        float h1 = x.y * av.y + cv.y; h1 = h1 > 0.f ? h1 : expm1f(h1);
        row[lane] = make_float2(h0, h1);
        float t = h0 * wv.x + h1 * wv.y;
        for (int off = 32; off; off >>= 1) t += __shfl_down(t, off);
        if (lane == 0) p[n] = t * inv_out[n];
    }
}

// fused: dvec[n] = inv_in[n]*sum_{in-edges} p[src] + bv
__global__ void k_dp(const int* __restrict__ csr_off, const int* __restrict__ csr_src,
                     const float* __restrict__ p, const float* __restrict__ inv_in,
                     const float* __restrict__ bv, float* dvec) {
    int n = blockIdx.x * blockDim.x + threadIdx.x;
    if (n < N_NODES) {
        int e0 = csr_off[n], e1 = csr_off[n + 1];
        float s = 0.f;
        for (int e = e0; e < e1; ++e) s += p[csr_src[e]];
        dvec[n] = s * inv_in[n] + bv[0];
    }
}

// per-graph pooling vec[g] = sum_{i<100} d*h2, plus global sum for mean
__global__ __launch_bounds__(128) void k_vec(const float* __restrict__ dvec,
                                             const float* __restrict__ h2,
                                             float* vec, float* meansum) {
    __shared__ float part[2];
    int g = blockIdx.x, j = threadIdx.x;
    int base = g * NPG;
    float acc = 0.f;
    for (int i = 0; i < NPG; ++i)
        acc += dvec[base + i] * h2[(size_t)(base + i) * HID + j];
    vec[g * HID + j] = acc;
    float t = acc;
    for (int off = 32; off; off >>= 1) t += __shfl_down(t, off);
    if ((j & 63) == 0) part[j >> 6] = t;
    __syncthreads();
    if (j == 0) atomicAdd(meansum, part[0] + part[1]);
}

// shrink+tanh then y3 = hg0 @ Wg + bg, fused BN stats
__global__ __launch_bounds__(128) void k_g1(const float* __restrict__ vec,
                                            const float* __restrict__ meansum,
                                            const float* __restrict__ Wg,
                                            const float* __restrict__ bg,
                                            float* y3, float* sums, float* sqs) {
    __shared__ float ws[HID * HID];
    __shared__ float rows[HID];
    int g = blockIdx.x, j = threadIdx.x;
    for (int k = 0; k < HID; ++k) ws[k * HID + j] = Wg[k * HID + j];
    float mean = meansum[0] * (1.f / (B_GR * HID));
    float v = vec[g * HID + j];
    float sh = fmaxf(v - mean, 0.f) - fmaxf(-v - mean, 0.f);
    rows[j] = tanhf(sh);
    __syncthreads();
    float acc = 0.f;
#pragma unroll 8
    for (int k = 0; k < HID; ++k) acc += rows[k] * ws[k * HID + j];
    float y = acc + bg[j];
    y3[g * HID + j] = y;
    atomicAdd(&sums[j], y);
    atomicAdd(&sqs[j], y * y);
}

// final: hg = tanh(bn(y3)), out = tanh(hg @ Wc + bc)
__global__ __launch_bounds__(128) void k_out(const float* __restrict__ y3,
                                             const float* __restrict__ a,
                                             const float* __restrict__ c,
                                             const float* __restrict__ Wc,
                                             const float* __restrict__ bc,
                                             float* out) {
    __shared__ float hg[HID];
    int g = blockIdx.x, j = threadIdx.x;
    hg[j] = tanhf(y3[g * HID + j] * a[j] + c[j]);
    __syncthreads();
    if (j < NC) {
        float acc = 0.f;
        for (int k = 0; k < HID; ++k) acc += hg[k] * Wc[k * NC + j];
        out[g * NC + j] = tanhf(acc + bc[j]);
    }
}

extern "C" void kernel_launch(void* const* d_in, const int* in_sizes, int n_in,
                              void* d_out, int out_size, void* d_ws, size_t ws_size,
                              hipStream_t stream) {
    const int*   src = (const int*)d_in[0];
    const int*   dst = (const int*)d_in[1];
    const float* W1  = (const float*)d_in[3];
    const float* b1  = (const float*)d_in[4];
    const float* g1  = (const float*)d_in[5];
    const float* be1 = (const float*)d_in[6];
    const float* W2  = (const float*)d_in[7];
    const float* b2  = (const float*)d_in[8];
    const float* g2  = (const float*)d_in[9];
    const float* be2 = (const float*)d_in[10];
    const float* Wv  = (const float*)d_in[11];
    const float* bv  = (const float*)d_in[12];
    const float* Wg  = (const float*)d_in[15];
    const float* bg  = (const float*)d_in[16];
    const float* g3  = (const float*)d_in[17];
    const float* be3 = (const float*)d_in[18];
    const float* Wc  = (const float*)d_in[19];
    const float* bc  = (const float*)d_in[20];
    float* out = (float*)d_out;

    char* ws = (char*)d_ws;
    size_t off = 0;
    auto carve = [&](size_t bytes) -> char* {
        char* pp = ws + off;
        off = (off + bytes + 255) & ~(size_t)255;
        return pp;
    };
    // ---- zeroed region (contiguous from start) ----
    int*   in_deg  = (int*)  carve(N_NODES * 4);
    int*   out_deg = (int*)  carve(N_NODES * 4);
    float* agg20   = (float*)carve((size_t)N_NODES * IND * 4);
    float* stats   = (float*)carve(2048 * 4);
    size_t zbytes = off;
    // ---- fully-overwritten region ----
    int*   idx     = (int*)  carve(N_NODES * 4);
    float* inv_in  = (float*)carve(N_NODES * 4);
    float* inv_out = (float*)carve(N_NODES * 4);
    float* pbuf    = (float*)carve(N_NODES * 4);
    float* dvec    = (float*)carve(N_NODES * 4);   // aliases cursor (cursor dead after scatter)
    int*   cursor  = (int*)dvec;
    float* vec     = (float*)carve((size_t)B_GR * HID * 4);
    float* y3      = (float*)carve((size_t)B_GR * HID * 4);
    int*   bsum    = (int*)  carve(512 * 4);
    int*   boff    = (int*)  carve(512 * 4);
    int*   csr_off = (int*)  carve((size_t)(N_NODES + 1) * 4);
    int*   csr_src = (int*)  carve((size_t)N_EDGES * 4);
    float* bufA    = (float*)carve((size_t)N_NODES * HID * 4);  // h1s -> y2 -> h2
    float* bufB    = (float*)carve((size_t)N_NODES * HID * 4);  // agg2

    float* sums2 = stats + 0;    float* sq2 = stats + 128;
    float* a2    = stats + 256;  float* c2  = stats + 384;
    float* sums3 = stats + 512;  float* sq3 = stats + 640;
    float* a3    = stats + 768;  float* c3  = stats + 896;
    float* meansum = stats + 1024;
    float* s20   = stats + 1056;   // 20
    float* Mbuf  = stats + 1088;   // 210
    float* a1    = stats + 1312;   // 128
    float* c1    = stats + 1440;   // 128

    hipMemsetAsync(d_ws, 0, zbytes, stream);

    k_deg<<<(N_EDGES + 255) / 256, 256, 0, stream>>>(src, dst, in_deg, out_deg);
    k_nodeprep<<<(N_NODES + 255) / 256, 256, 0, stream>>>(in_deg, out_deg, inv_in, inv_out, idx);
    // CSR build
    k_scan1<<<NBLK_SCAN, 256, 0, stream>>>(in_deg, csr_off, bsum);
    k_scan2<<<1, 512, 0, stream>>>(bsum, boff);
    k_scan3<<<NBLK_SCAN, 256, 0, stream>>>(csr_off, boff, cursor);
    // fused scatter + layer-1 one-hot aggregation (single edge pass)
    k_scatter_l1<<<(N_EDGES + 255) / 256, 256, 0, stream>>>(src, dst, idx, inv_out,
                                                            cursor, csr_src, agg20);
    // BN1 via moments, then fused layer-1 pass
    k_mom<<<320, 256, 0, stream>>>(agg20, inv_in, s20, Mbuf);
    k_bn1fin<<<1, 128, 0, stream>>>(s20, Mbuf, W1, b1, g1, be1, a1, c1);
    k_l1f<<<N_NODES / 64, 256, 0, stream>>>(agg20, inv_in, inv_out, W1, b1, a1, c1, bufA);
    // layer-2 aggregation: block-per-graph, h1 slice in LDS
    k_agg2<<<B_GR, 512, 0, stream>>>(csr_off, csr_src, bufA, bufB);
    // layer 2 GEMM v4 (conflict-free, 512 thr, 128-row tiles)
    k_l2v4<<<N_NODES / 128, 512, 0, stream>>>(bufB, inv_in, W2, b2, bufA, sums2, sq2);
    k_bnfin<<<1, 128, 0, stream>>>(sums2, sq2, g2, be2, (float)N_NODES, a2, c2);
    k_elu2_p<<<1024, 256, 0, stream>>>(bufA, a2, c2, inv_out, Wv, pbuf);
    // value head + pooling
    k_dp<<<(N_NODES + 255) / 256, 256, 0, stream>>>(csr_off, csr_src, pbuf, inv_in, bv, dvec);
    k_vec<<<B_GR, 128, 0, stream>>>(dvec, bufA, vec, meansum);
    k_g1<<<B_GR, 128, 0, stream>>>(vec, meansum, Wg, bg, y3, sums3, sq3);
    k_bnfin<<<1, 128, 0, stream>>>(sums3, sq3, g3, be3, (float)B_GR, a3, c3);
    k_out<<<B_GR, 128, 0, stream>>>(y3, a3, c3, Wc, bc, out);
}

// Round 10
// 351.123 us; speedup vs baseline: 1.0226x; 1.0226x over previous
//
#include <hip/hip_runtime.h>
#include <hip/hip_bf16.h>
#include <math.h>

#define N_NODES 80000
#define N_EDGES 640000
#define B_GR 800
#define NPG 100
#define HID 128
#define NC 10
#define IND 20
#define BN_EPS 1e-5f
#define NBLK_SCAN 313   // ceil(80000/256)

// ---------- degree counting ----------
__global__ void k_deg(const int* __restrict__ src, const int* __restrict__ dst,
                      int* in_deg, int* out_deg) {
    int e = blockIdx.x * blockDim.x + threadIdx.x;
    if (e < N_EDGES) {
        atomicAdd(&in_deg[dst[e]], 1);
        atomicAdd(&out_deg[src[e]], 1);
    }
}

__global__ void k_nodeprep(const int* __restrict__ in_deg, const int* __restrict__ out_deg,
                           float* inv_in, float* inv_out, int* idx) {
    int n = blockIdx.x * blockDim.x + threadIdx.x;
    if (n < N_NODES) {
        float fi = (float)in_deg[n];
        float fo = (float)out_deg[n];
        inv_in[n]  = rsqrtf(fmaxf(fi, 1.f));
        inv_out[n] = rsqrtf(fmaxf(fo, 1.f));
        int k = in_deg[n]; if (k > IND - 1) k = IND - 1;
        idx[n] = k;
    }
}

// ---------- CSR build: exclusive scan of in_deg, then scatter ----------
__global__ __launch_bounds__(256) void k_scan1(const int* __restrict__ in, int* part, int* bsum) {
    __shared__ int s[256];
    int t = threadIdx.x, i = blockIdx.x * 256 + t;
    int v = (i < N_NODES) ? in[i] : 0;
    s[t] = v; __syncthreads();
    for (int d = 1; d < 256; d <<= 1) {
        int x = (t >= d) ? s[t - d] : 0;
        __syncthreads();
        s[t] += x;
        __syncthreads();
    }
    if (i < N_NODES) part[i] = s[t] - v;            // exclusive partial
    if (t == 255) bsum[blockIdx.x] = s[255];        // block total
}

__global__ __launch_bounds__(512) void k_scan2(const int* __restrict__ bsum, int* boff) {
    __shared__ int s[512];
    int t = threadIdx.x;
    int v = (t < NBLK_SCAN) ? bsum[t] : 0;
    s[t] = v; __syncthreads();
    for (int d = 1; d < 512; d <<= 1) {
        int x = (t >= d) ? s[t - d] : 0;
        __syncthreads();
        s[t] += x;
        __syncthreads();
    }
    if (t < NBLK_SCAN) boff[t] = s[t] - v;          // exclusive
}

__global__ __launch_bounds__(256) void k_scan3(int* csr_off, const int* __restrict__ boff,
                                               int* cursor) {
    int i = blockIdx.x * 256 + threadIdx.x;
    if (i < N_NODES) {
        int v = csr_off[i] + boff[blockIdx.x];
        csr_off[i] = v;
        cursor[i] = v;
    }
    if (i == 0) csr_off[N_NODES] = N_EDGES;
}

// fused: CSR scatter + layer-1 one-hot aggregation (single edge pass)
__global__ void k_scatter_l1(const int* __restrict__ src, const int* __restrict__ dst,
                             const int* __restrict__ idx, const float* __restrict__ inv_out,
                             int* cursor, int* csr_src, float* agg20) {
    int e = blockIdx.x * blockDim.x + threadIdx.x;
    if (e < N_EDGES) {
        int s = src[e], t = dst[e];
        int pos = atomicAdd(&cursor[t], 1);
        csr_src[pos] = s;
        atomicAdd(&agg20[t * IND + idx[s]], inv_out[s]);
    }
}

// ---------- BN1 stats via moments ----------
#define MOM_CHUNK 64
__global__ __launch_bounds__(256) void k_mom(const float* __restrict__ agg20,
                                             const float* __restrict__ inv_in,
                                             float* s20, float* Mbuf) {
    __shared__ float rows[MOM_CHUNK * IND];
    __shared__ float w1s[MOM_CHUNK], w2s[MOM_CHUNK];
    int t = threadIdx.x;
    int k = 0, l = 0;
    bool isM = (t < 210), isS = (t >= 210 && t < 230);
    if (isM) {
        int idx = t, kk = 0;
        while (idx >= IND - kk) { idx -= IND - kk; ++kk; }
        k = kk; l = kk + idx;
    } else if (isS) {
        k = t - 210;
    }
    float acc = 0.f;
    for (int c = blockIdx.x; c < N_NODES / MOM_CHUNK; c += gridDim.x) {
        __syncthreads();
        for (int i = t * 4; i < MOM_CHUNK * IND; i += 1024)
            *(float4*)&rows[i] = *(const float4*)&agg20[(size_t)c * MOM_CHUNK * IND + i];
        if (t < MOM_CHUNK) {
            float v = inv_in[c * MOM_CHUNK + t];
            w1s[t] = v; w2s[t] = v * v;
        }
        __syncthreads();
        if (isM) {
            for (int i = 0; i < MOM_CHUNK; ++i)
                acc += w2s[i] * rows[i * IND + k] * rows[i * IND + l];
        } else if (isS) {
            for (int i = 0; i < MOM_CHUNK; ++i)
                acc += w1s[i] * rows[i * IND + k];
        }
    }
    if (isM) atomicAdd(&Mbuf[t], acc);
    else if (isS) atomicAdd(&s20[t - 210], acc);
}

// a1,c1 from moments (128 threads: each stages TWO sM entries; first 20 stage ss)
__global__ void k_bn1fin(const float* __restrict__ s20, const float* __restrict__ Mbuf,
                         const float* __restrict__ W1, const float* __restrict__ b1,
                         const float* __restrict__ g1, const float* __restrict__ be1,
                         float* a1, float* c1) {
    __shared__ float sM[210], ss[IND];
    int j = threadIdx.x;
    if (j < 210) sM[j] = Mbuf[j];
    if (j + 128 < 210) sM[j + 128] = Mbuf[j + 128];
    if (j < IND) ss[j] = s20[j];
    __syncthreads();
    float w[IND];
#pragma unroll
    for (int k = 0; k < IND; ++k) w[k] = W1[k * HID + j];
    float tj = 0.f;
#pragma unroll
    for (int k = 0; k < IND; ++k) tj += ss[k] * w[k];
    float q = 0.f;
    int idx = 0;
#pragma unroll
    for (int k = 0; k < IND; ++k) {
        q += sM[idx] * w[k] * w[k]; ++idx;
#pragma unroll
        for (int l = k + 1; l < IND; ++l) { q += 2.f * sM[idx] * w[k] * w[l]; ++idx; }
    }
    float bj = b1[j];
    const float Nf = (float)N_NODES;
    float mean = (tj + Nf * bj) / Nf;
    float ey2  = (q + 2.f * bj * tj + Nf * bj * bj) / Nf;
    float var  = ey2 - mean * mean;
    float aj = g1[j] / sqrtf(var + BN_EPS);
    a1[j] = aj;
    c1[j] = be1[j] - mean * aj;
}

// ---------- fused layer 1: h1s = elu(bn(inv_in*(agg20@W1)+b1)) * inv_out ----------
__global__ __launch_bounds__(256) void k_l1f(const float* __restrict__ agg20,
                                             const float* __restrict__ inv_in,
                                             const float* __restrict__ inv_out,
                                             const float* __restrict__ W1,
                                             const float* __restrict__ b1,
                                             const float* __restrict__ a1,
                                             const float* __restrict__ c1,
                                             float* __restrict__ h1s) {
    __shared__ float ws[IND * HID];   // 10 KB
    int t = threadIdx.x;
    for (int i = t * 4; i < IND * HID; i += 1024)
        *(float4*)&ws[i] = *(const float4*)&W1[i];
    __syncthreads();
    int tx = t & 15, ty = t >> 4;
    int c0 = tx * 8;
    float4 ba = *(const float4*)(b1 + c0);
    float4 bb = *(const float4*)(b1 + c0 + 4);
    float4 aa = *(const float4*)(a1 + c0);
    float4 ab = *(const float4*)(a1 + c0 + 4);
    float4 ca = *(const float4*)(c1 + c0);
    float4 cb = *(const float4*)(c1 + c0 + 4);

    int row0 = blockIdx.x * 64 + ty * 4;
    const float* xr0 = agg20 + (size_t)row0 * IND;
    const float* xr1 = xr0 + IND;
    const float* xr2 = xr1 + IND;
    const float* xr3 = xr2 + IND;
    float acc[4][8];
#pragma unroll
    for (int r = 0; r < 4; ++r)
#pragma unroll
        for (int c = 0; c < 8; ++c) acc[r][c] = 0.f;

#pragma unroll
    for (int k = 0; k < IND; k += 4) {
        float4 x0 = *(const float4*)(xr0 + k);
        float4 x1 = *(const float4*)(xr1 + k);
        float4 x2 = *(const float4*)(xr2 + k);
        float4 x3 = *(const float4*)(xr3 + k);
#pragma unroll
        for (int kk = 0; kk < 4; ++kk) {
            float4 wa = *(const float4*)&ws[(k + kk) * HID + c0];
            float4 wb = *(const float4*)&ws[(k + kk) * HID + c0 + 4];
            float xk0 = (kk == 0) ? x0.x : (kk == 1) ? x0.y : (kk == 2) ? x0.z : x0.w;
            float xk1 = (kk == 0) ? x1.x : (kk == 1) ? x1.y : (kk == 2) ? x1.z : x1.w;
            float xk2 = (kk == 0) ? x2.x : (kk == 1) ? x2.y : (kk == 2) ? x2.z : x2.w;
            float xk3 = (kk == 0) ? x3.x : (kk == 1) ? x3.y : (kk == 2) ? x3.z : x3.w;
            acc[0][0] += xk0 * wa.x; acc[0][1] += xk0 * wa.y;
            acc[0][2] += xk0 * wa.z; acc[0][3] += xk0 * wa.w;
            acc[0][4] += xk0 * wb.x; acc[0][5] += xk0 * wb.y;
            acc[0][6] += xk0 * wb.z; acc[0][7] += xk0 * wb.w;
            acc[1][0] += xk1 * wa.x; acc[1][1] += xk1 * wa.y;
            acc[1][2] += xk1 * wa.z; acc[1][3] += xk1 * wa.w;
            acc[1][4] += xk1 * wb.x; acc[1][5] += xk1 * wb.y;
            acc[1][6] += xk1 * wb.z; acc[1][7] += xk1 * wb.w;
            acc[2][0] += xk2 * wa.x; acc[2][1] += xk2 * wa.y;
            acc[2][2] += xk2 * wa.z; acc[2][3] += xk2 * wa.w;
            acc[2][4] += xk2 * wb.x; acc[2][5] += xk2 * wb.y;
            acc[2][6] += xk2 * wb.z; acc[2][7] += xk2 * wb.w;
            acc[3][0] += xk3 * wa.x; acc[3][1] += xk3 * wa.y;
            acc[3][2] += xk3 * wa.z; acc[3][3] += xk3 * wa.w;
            acc[3][4] += xk3 * wb.x; acc[3][5] += xk3 * wb.y;
            acc[3][6] += xk3 * wb.z; acc[3][7] += xk3 * wb.w;
        }
    }
    float4 iv = *(const float4*)(inv_in + row0);
    float4 ov = *(const float4*)(inv_out + row0);
#pragma unroll
    for (int r = 0; r < 4; ++r) {
        float ivr = (r == 0) ? iv.x : (r == 1) ? iv.y : (r == 2) ? iv.z : iv.w;
        float ovr = (r == 0) ? ov.x : (r == 1) ? ov.y : (r == 2) ? ov.z : ov.w;
        float y[8];
        y[0] = acc[r][0] * ivr + ba.x; y[1] = acc[r][1] * ivr + ba.y;
        y[2] = acc[r][2] * ivr + ba.z; y[3] = acc[r][3] * ivr + ba.w;
        y[4] = acc[r][4] * ivr + bb.x; y[5] = acc[r][5] * ivr + bb.y;
        y[6] = acc[r][6] * ivr + bb.z; y[7] = acc[r][7] * ivr + bb.w;
        float z[8];
        z[0] = y[0] * aa.x + ca.x; z[1] = y[1] * aa.y + ca.y;
        z[2] = y[2] * aa.z + ca.z; z[3] = y[3] * aa.w + ca.w;
        z[4] = y[4] * ab.x + cb.x; z[5] = y[5] * ab.y + cb.y;
        z[6] = y[6] * ab.z + cb.z; z[7] = y[7] * ab.w + cb.w;
#pragma unroll
        for (int c = 0; c < 8; ++c) {
            float h = z[c] > 0.f ? z[c] : expm1f(z[c]);
            z[c] = h * ovr;
        }
        float* yr = h1s + (size_t)(row0 + r) * HID + c0;
        *(float4*)yr = make_float4(z[0], z[1], z[2], z[3]);
        *(float4*)(yr + 4) = make_float4(z[4], z[5], z[6], z[7]);
    }
}

// ---------- layer-2 aggregation v3: block per graph, h1 slice staged in LDS ----------
__global__ __launch_bounds__(512) void k_agg2(const int* __restrict__ csr_off,
                                              const int* __restrict__ csr_src,
                                              const float* __restrict__ h1s,
                                              float* __restrict__ agg2) {
    __shared__ float sh[NPG * HID];   // 51200 B
    int t = threadIdx.x;
    int g = blockIdx.x;
    int gbase = g * NPG;

    const float4* srcp = (const float4*)(h1s + (size_t)gbase * HID);
    float4* shp = (float4*)sh;
    for (int i = t; i < (NPG * HID) / 4; i += 512)
        shp[i] = srcp[i];
    __syncthreads();

    int wv = t >> 6, lane = t & 63;
    for (int r = wv; r < NPG; r += 8) {
        int n = gbase + r;
        int e0 = csr_off[n], e1 = csr_off[n + 1];
        float ax = 0.f, ay = 0.f;
        int e = e0;
        for (; e + 4 <= e1; e += 4) {
            int s0 = csr_src[e]     - gbase;
            int s1 = csr_src[e + 1] - gbase;
            int s2 = csr_src[e + 2] - gbase;
            int s3 = csr_src[e + 3] - gbase;
            float2 v0 = *(const float2*)&sh[s0 * HID + lane * 2];
            float2 v1 = *(const float2*)&sh[s1 * HID + lane * 2];
            float2 v2 = *(const float2*)&sh[s2 * HID + lane * 2];
            float2 v3 = *(const float2*)&sh[s3 * HID + lane * 2];
            ax += (v0.x + v1.x) + (v2.x + v3.x);
            ay += (v0.y + v1.y) + (v2.y + v3.y);
        }
        for (; e < e1; ++e) {
            int s = csr_src[e] - gbase;
            float2 v = *(const float2*)&sh[s * HID + lane * 2];
            ax += v.x; ay += v.y;
        }
        *(float2*)(agg2 + (size_t)n * HID + lane * 2) = make_float2(ax, ay);
    }
}

// ---------- BN finalize (layers 2,3) ----------
__global__ void k_bnfin(const float* sums, const float* sqs,
                        const float* gamma, const float* beta,
                        float cnt, float* a, float* c) {
    int j = threadIdx.x;
    float mu  = sums[j] / cnt;
    float var = sqs[j] / cnt - mu * mu;
    float aj  = gamma[j] / sqrtf(var + BN_EPS);
    a[j] = aj;
    c[j] = beta[j] - mu * aj;
}

// ---------- layer 2 GEMM v5: split-N (2 col-halves), 32KB LDS, 4 blocks/CU ----------
// Block = (tile, half): 128 rows x 64 cols. 512 thr: tx=t&15 (4 cols), ty=t>>4 (4 rows).
// LDS W reads: 16 lanes x float4 covering 64 contiguous dwords -> 2 lanes/bank (free).
__global__ __launch_bounds__(512) void k_l2v5(const float* __restrict__ xin,
                                              const float* __restrict__ inv_in,
                                              const float* __restrict__ W,
                                              const float* __restrict__ bvec,
                                              float* __restrict__ yout,
                                              float* sums, float* sqs) {
    __shared__ float ws[HID * 64];   // 32 KB -> 4 blocks/CU (wave-capped), 32 waves/CU
    int t = threadIdx.x;
    int tile = blockIdx.x >> 1;
    int half = blockIdx.x & 1;
    int cbase = half * 64;
    for (int i = t; i < HID * 16; i += 512) {       // 2048 float4s
        int k = i >> 4;
        int c4 = (i & 15) << 2;
        *(float4*)&ws[k * 64 + c4] = *(const float4*)&W[k * HID + cbase + c4];
    }
    __syncthreads();

    int tx = t & 15;
    int ty = t >> 4;
    int c0 = tx * 4;
    float4 ba = *(const float4*)(bvec + cbase + c0);
    float csum[4], csq[4];
#pragma unroll
    for (int c = 0; c < 4; ++c) { csum[c] = 0.f; csq[c] = 0.f; }

    int row0 = tile * 128 + ty * 4;
    const float* xr0 = xin + (size_t)row0 * HID;
    const float* xr1 = xr0 + HID;
    const float* xr2 = xr1 + HID;
    const float* xr3 = xr2 + HID;
    float acc[4][4];
#pragma unroll
    for (int r = 0; r < 4; ++r)
#pragma unroll
        for (int c = 0; c < 4; ++c) acc[r][c] = 0.f;

#pragma unroll 4
    for (int k = 0; k < HID; k += 4) {
        float4 x0 = *(const float4*)(xr0 + k);
        float4 x1 = *(const float4*)(xr1 + k);
        float4 x2 = *(const float4*)(xr2 + k);
        float4 x3 = *(const float4*)(xr3 + k);
#pragma unroll
        for (int kk = 0; kk < 4; ++kk) {
            float4 wa = *(const float4*)&ws[(k + kk) * 64 + c0];
            float xk0 = (kk == 0) ? x0.x : (kk == 1) ? x0.y : (kk == 2) ? x0.z : x0.w;
            float xk1 = (kk == 0) ? x1.x : (kk == 1) ? x1.y : (kk == 2) ? x1.z : x1.w;
            float xk2 = (kk == 0) ? x2.x : (kk == 1) ? x2.y : (kk == 2) ? x2.z : x2.w;
            float xk3 = (kk == 0) ? x3.x : (kk == 1) ? x3.y : (kk == 2) ? x3.z : x3.w;
            acc[0][0] += xk0 * wa.x; acc[0][1] += xk0 * wa.y;
            acc[0][2] += xk0 * wa.z; acc[0][3] += xk0 * wa.w;
            acc[1][0] += xk1 * wa.x; acc[1][1] += xk1 * wa.y;
            acc[1][2] += xk1 * wa.z; acc[1][3] += xk1 * wa.w;
            acc[2][0] += xk2 * wa.x; acc[2][1] += xk2 * wa.y;
            acc[2][2] += xk2 * wa.z; acc[2][3] += xk2 * wa.w;
            acc[3][0] += xk3 * wa.x; acc[3][1] += xk3 * wa.y;
            acc[3][2] += xk3 * wa.z; acc[3][3] += xk3 * wa.w;
        }
    }
    float4 iv = *(const float4*)(inv_in + row0);
#pragma unroll
    for (int r = 0; r < 4; ++r) {
        float ivr = (r == 0) ? iv.x : (r == 1) ? iv.y : (r == 2) ? iv.z : iv.w;
        float y0 = acc[r][0] * ivr + ba.x;
        float y1 = acc[r][1] * ivr + ba.y;
        float y2 = acc[r][2] * ivr + ba.z;
        float y3 = acc[r][3] * ivr + ba.w;
        csum[0] += y0; csq[0] += y0 * y0;
        csum[1] += y1; csq[1] += y1 * y1;
        csum[2] += y2; csq[2] += y2 * y2;
        csum[3] += y3; csq[3] += y3 * y3;
        *(float4*)(yout + (size_t)(row0 + r) * HID + cbase + c0) = make_float4(y0, y1, y2, y3);
    }

    // column stats: reuse ws. sums ws[0..2047], sqs ws[2048..4095]
    __syncthreads();
#pragma unroll
    for (int c = 0; c < 4; ++c) {
        ws[ty * 64 + c0 + c] = csum[c];
        ws[2048 + ty * 64 + c0 + c] = csq[c];
    }
    __syncthreads();
    if (t < 64) {
        float s1 = 0.f, s2 = 0.f;
#pragma unroll
        for (int r = 0; r < 32; ++r) {
            s1 += ws[r * 64 + t];
            s2 += ws[2048 + r * 64 + t];
        }
        atomicAdd(&sums[cbase + t], s1);
        atomicAdd(&sqs[cbase + t], s2);
    }
}

// in-place y2 -> h2 (elu), p[n] = inv_out[n]*dot(h2[n],Wv); wave per row
__global__ __launch_bounds__(256) void k_elu2_p(float* buf,
                                                const float* __restrict__ a,
                                                const float* __restrict__ c,
                                                const float* __restrict__ inv_out,
                                                const float* __restrict__ Wv,
                                                float* __restrict__ p) {
    int lane = threadIdx.x & 63;
    int wid = (blockIdx.x * blockDim.x + threadIdx.x) >> 6;
    int nw = (gridDim.x * blockDim.x) >> 6;
    float2 av = *(const float2*)(a + lane * 2);
    float2 cv = *(const float2*)(c + lane * 2);
    float2 wv = *(const float2*)(Wv + lane * 2);
    for (int n = wid; n < N_NODES; n += nw) {
        float2* row = (float2*)(buf + (size_t)n * HID);
        float2 x = row[lane];
        float h0 = x.x * av.x + cv.x; h0 = h0 > 0.f ? h0 : expm1f(h0);
        float h1 = x.y * av.y + cv.y; h1 = h1 > 0.f ? h1 : expm1f(h1);
        row[lane] = make_float2(h0, h1);
        float t = h0 * wv.x + h1 * wv.y;
        for (int off = 32; off; off >>= 1) t += __shfl_down(t, off);
        if (lane == 0) p[n] = t * inv_out[n];
    }
}

// fused: dvec[n] = inv_in[n]*sum_{in-edges} p[src] + bv
__global__ void k_dp(const int* __restrict__ csr_off, const int* __restrict__ csr_src,
                     const float* __restrict__ p, const float* __restrict__ inv_in,
                     const float* __restrict__ bv, float* dvec) {
    int n = blockIdx.x * blockDim.x + threadIdx.x;
    if (n < N_NODES) {
        int e0 = csr_off[n], e1 = csr_off[n + 1];
        float s = 0.f;
        for (int e = e0; e < e1; ++e) s += p[csr_src[e]];
        dvec[n] = s * inv_in[n] + bv[0];
    }
}

// per-graph pooling vec[g] = sum_{i<100} d*h2, plus global sum for mean
__global__ __launch_bounds__(128) void k_vec(const float* __restrict__ dvec,
                                             const float* __restrict__ h2,
                                             float* vec, float* meansum) {
    __shared__ float part[2];
    int g = blockIdx.x, j = threadIdx.x;
    int base = g * NPG;
    float acc = 0.f;
    for (int i = 0; i < NPG; ++i)
        acc += dvec[base + i] * h2[(size_t)(base + i) * HID + j];
    vec[g * HID + j] = acc;
    float t = acc;
    for (int off = 32; off; off >>= 1) t += __shfl_down(t, off);
    if ((j & 63) == 0) part[j >> 6] = t;
    __syncthreads();
    if (j == 0) atomicAdd(meansum, part[0] + part[1]);
}

// shrink+tanh then y3 = hg0 @ Wg + bg, fused BN stats
__global__ __launch_bounds__(128) void k_g1(const float* __restrict__ vec,
                                            const float* __restrict__ meansum,
                                            const float* __restrict__ Wg,
                                            const float* __restrict__ bg,
                                            float* y3, float* sums, float* sqs) {
    __shared__ float ws[HID * HID];
    __shared__ float rows[HID];
    int g = blockIdx.x, j = threadIdx.x;
    for (int k = 0; k < HID; ++k) ws[k * HID + j] = Wg[k * HID + j];
    float mean = meansum[0] * (1.f / (B_GR * HID));
    float v = vec[g * HID + j];
    float sh = fmaxf(v - mean, 0.f) - fmaxf(-v - mean, 0.f);
    rows[j] = tanhf(sh);
    __syncthreads();
    float acc = 0.f;
#pragma unroll 8
    for (int k = 0; k < HID; ++k) acc += rows[k] * ws[k * HID + j];
    float y = acc + bg[j];
    y3[g * HID + j] = y;
    atomicAdd(&sums[j], y);
    atomicAdd(&sqs[j], y * y);
}

// final: hg = tanh(bn(y3)), out = tanh(hg @ Wc + bc)
__global__ __launch_bounds__(128) void k_out(const float* __restrict__ y3,
                                             const float* __restrict__ a,
                                             const float* __restrict__ c,
                                             const float* __restrict__ Wc,
                                             const float* __restrict__ bc,
                                             float* out) {
    __shared__ float hg[HID];
    int g = blockIdx.x, j = threadIdx.x;
    hg[j] = tanhf(y3[g * HID + j] * a[j] + c[j]);
    __syncthreads();
    if (j < NC) {
        float acc = 0.f;
        for (int k = 0; k < HID; ++k) acc += hg[k] * Wc[k * NC + j];
        out[g * NC + j] = tanhf(acc + bc[j]);
    }
}

extern "C" void kernel_launch(void* const* d_in, const int* in_sizes, int n_in,
                              void* d_out, int out_size, void* d_ws, size_t ws_size,
                              hipStream_t stream) {
    const int*   src = (const int*)d_in[0];
    const int*   dst = (const int*)d_in[1];
    const float* W1  = (const float*)d_in[3];
    const float* b1  = (const float*)d_in[4];
    const float* g1  = (const float*)d_in[5];
    const float* be1 = (const float*)d_in[6];
    const float* W2  = (const float*)d_in[7];
    const float* b2  = (const float*)d_in[8];
    const float* g2  = (const float*)d_in[9];
    const float* be2 = (const float*)d_in[10];
    const float* Wv  = (const float*)d_in[11];
    const float* bv  = (const float*)d_in[12];
    const float* Wg  = (const float*)d_in[15];
    const float* bg  = (const float*)d_in[16];
    const float* g3  = (const float*)d_in[17];
    const float* be3 = (const float*)d_in[18];
    const float* Wc  = (const float*)d_in[19];
    const float* bc  = (const float*)d_in[20];
    float* out = (float*)d_out;

    char* ws = (char*)d_ws;
    size_t off = 0;
    auto carve = [&](size_t bytes) -> char* {
        char* pp = ws + off;
        off = (off + bytes + 255) & ~(size_t)255;
        return pp;
    };
    // ---- zeroed region (contiguous from start) ----
    int*   in_deg  = (int*)  carve(N_NODES * 4);
    int*   out_deg = (int*)  carve(N_NODES * 4);
    float* agg20   = (float*)carve((size_t)N_NODES * IND * 4);
    float* stats   = (float*)carve(2048 * 4);
    size_t zbytes = off;
    // ---- fully-overwritten region ----
    int*   idx     = (int*)  carve(N_NODES * 4);
    float* inv_in  = (float*)carve(N_NODES * 4);
    float* inv_out = (float*)carve(N_NODES * 4);
    float* pbuf    = (float*)carve(N_NODES * 4);
    float* dvec    = (float*)carve(N_NODES * 4);   // aliases cursor (cursor dead after scatter)
    int*   cursor  = (int*)dvec;
    float* vec     = (float*)carve((size_t)B_GR * HID * 4);
    float* y3      = (float*)carve((size_t)B_GR * HID * 4);
    int*   bsum    = (int*)  carve(512 * 4);
    int*   boff    = (int*)  carve(512 * 4);
    int*   csr_off = (int*)  carve((size_t)(N_NODES + 1) * 4);
    int*   csr_src = (int*)  carve((size_t)N_EDGES * 4);
    float* bufA    = (float*)carve((size_t)N_NODES * HID * 4);  // h1s -> y2 -> h2
    float* bufB    = (float*)carve((size_t)N_NODES * HID * 4);  // agg2

    float* sums2 = stats + 0;    float* sq2 = stats + 128;
    float* a2    = stats + 256;  float* c2  = stats + 384;
    float* sums3 = stats + 512;  float* sq3 = stats + 640;
    float* a3    = stats + 768;  float* c3  = stats + 896;
    float* meansum = stats + 1024;
    float* s20   = stats + 1056;   // 20
    float* Mbuf  = stats + 1088;   // 210
    float* a1    = stats + 1312;   // 128
    float* c1    = stats + 1440;   // 128

    hipMemsetAsync(d_ws, 0, zbytes, stream);

    k_deg<<<(N_EDGES + 255) / 256, 256, 0, stream>>>(src, dst, in_deg, out_deg);
    k_nodeprep<<<(N_NODES + 255) / 256, 256, 0, stream>>>(in_deg, out_deg, inv_in, inv_out, idx);
    // CSR build
    k_scan1<<<NBLK_SCAN, 256, 0, stream>>>(in_deg, csr_off, bsum);
    k_scan2<<<1, 512, 0, stream>>>(bsum, boff);
    k_scan3<<<NBLK_SCAN, 256, 0, stream>>>(csr_off, boff, cursor);
    // fused scatter + layer-1 one-hot aggregation (single edge pass)
    k_scatter_l1<<<(N_EDGES + 255) / 256, 256, 0, stream>>>(src, dst, idx, inv_out,
                                                            cursor, csr_src, agg20);
    // BN1 via moments, then fused layer-1 pass
    k_mom<<<320, 256, 0, stream>>>(agg20, inv_in, s20, Mbuf);
    k_bn1fin<<<1, 128, 0, stream>>>(s20, Mbuf, W1, b1, g1, be1, a1, c1);
    k_l1f<<<N_NODES / 64, 256, 0, stream>>>(agg20, inv_in, inv_out, W1, b1, a1, c1, bufA);
    // layer-2 aggregation: block-per-graph, h1 slice in LDS
    k_agg2<<<B_GR, 512, 0, stream>>>(csr_off, csr_src, bufA, bufB);
    // layer 2 GEMM v5 (split-N: 625 tiles x 2 col-halves, 32KB LDS)
    k_l2v5<<<(N_NODES / 128) * 2, 512, 0, stream>>>(bufB, inv_in, W2, b2, bufA, sums2, sq2);
    k_bnfin<<<1, 128, 0, stream>>>(sums2, sq2, g2, be2, (float)N_NODES, a2, c2);
    k_elu2_p<<<1024, 256, 0, stream>>>(bufA, a2, c2, inv_out, Wv, pbuf);
    // value head + pooling
    k_dp<<<(N_NODES + 255) / 256, 256, 0, stream>>>(csr_off, csr_src, pbuf, inv_in, bv, dvec);
    k_vec<<<B_GR, 128, 0, stream>>>(dvec, bufA, vec, meansum);
    k_g1<<<B_GR, 128, 0, stream>>>(vec, meansum, Wg, bg, y3, sums3, sq3);
    k_bnfin<<<1, 128, 0, stream>>>(sums3, sq3, g3, be3, (float)B_GR, a3, c3);
    k_out<<<B_GR, 128, 0, stream>>>(y3, a3, c3, Wc, bc, out);
}